// Round 8
// baseline (2604.551 us; speedup 1.0000x reference)
//
#include <hip/hip_runtime.h>
#include <hip/hip_bf16.h>
#include <math.h>

typedef __hip_bfloat16 bf16;
typedef float  floatx16 __attribute__((ext_vector_type(16)));
typedef short  short8   __attribute__((ext_vector_type(8)));

#define Bn 4
#define NF 64
#define Hn 192
#define Wn 192
#define HWn (Hn*Wn)

// ---- weight pool element offsets (bf16 elements, relative to WPOOL) ----
#define WA_OC1  0
#define WA_OC2  73728
#define WA_FC   110592
#define WA_CAS1 147456
#define WA_CAS2 221184
#define WA_D1O  258048
#define WA_CDO  405504
#define WP_D1   552960
#define WP_CD   589824
// ---- bias pool float offsets ----
#define B_OC1  0
#define B_OC2  64
#define B_FC   128
#define B_CAS1 192
#define B_CAS2 256
#define B_D1O  320
#define B_CDO  536
#define B_D1P  752
#define B_CDP  816
// ---- ws byte offsets ----
#define BIAS_OFF  1024
#define WPOOL_OFF 5120
#define BUF_OFF   1261568          // 4K aligned, past weight pool
#define FEAT_BYTES 18874368        // 4*64*36864*2

__device__ __forceinline__ float b2f(bf16 v){ return __bfloat162float(v); }
__device__ __forceinline__ bf16  f2b(float v){ return __float2bfloat16(v); }
__device__ __forceinline__ float ld(const void* p, size_t i, int f32){
    if (f32) return ((const float*)p)[i];
    return b2f(((const bf16*)p)[i]);
}

union B8 { uint2 u2[2]; uint4 u4; short8 s8; };

struct P20 { const void* p[20]; int n[20]; };

// ---------------------------------------------------------------------------
// Dtype probe (established: inputs fp32-in-memory, bf16-valued)
// ---------------------------------------------------------------------------
__global__ void detect_kernel(P20 a, int* __restrict__ flags){
    int t = threadIdx.x;
    if (t >= 20) return;
    const unsigned short* u = (const unsigned short*)a.p[t];
    int n = a.n[t]; if (n > 512) n = 512;
    int f32 = 0;
    for (int i = 0; i < n; ++i){
        float v = __uint_as_float(((unsigned)u[i]) << 16);
        if (!(fabsf(v) < 1e3f)) f32 = 1;
    }
    flags[t] = f32;
}

// ---------------------------------------------------------------------------
// Prep: 3x3 conv weights -> bf16 MFMA A-frag layout, tap-major K.
// ---------------------------------------------------------------------------
__global__ void prep_convA(const void* __restrict__ src, const int* __restrict__ flags,
                           int fi, bf16* __restrict__ dst, int Cin, int CoutReal, int OCB)
{
    int idx = blockIdx.x*256 + threadIdx.x;
    int KK = Cin >> 4;
    int total = OCB*9*KK*512;
    if (idx >= total) return;
    int j  = idx & 7;
    int ko = (idx>>3) & 1;
    int m  = (idx>>4) & 31;
    int rest = idx >> 9;
    int kk = rest % KK; rest /= KK;
    int tap = rest % 9;
    int ocb = rest / 9;
    int oc = ocb*32 + m;
    int ci = kk*16 + ko*8 + j;
    float v = 0.f;
    if (oc < CoutReal) v = ld(src, ((size_t)oc*Cin + ci)*9 + tap, flags[fi]);
    dst[idx] = f2b(v);
}

// ---------------------------------------------------------------------------
// Prep: DCN projection weights -> A-frag layout, natural K = ci*9+tap (576).
// ---------------------------------------------------------------------------
__global__ void prep_projA(const void* __restrict__ src, const int* __restrict__ flags,
                           int fi, bf16* __restrict__ dst)
{
    int idx = blockIdx.x*256 + threadIdx.x;
    if (idx >= 2*36*512) return;
    int j  = idx & 7;
    int ko = (idx>>3) & 1;
    int m  = (idx>>4) & 31;
    int rest = idx >> 9;
    int kk = rest % 36;
    int ocb = rest / 36;
    int oc = ocb*32 + m;
    int k  = kk*16 + ko*8 + j;
    dst[idx] = f2b(ld(src, (size_t)oc*576 + k, flags[fi]));
}

// ---------------------------------------------------------------------------
// Prep: biases -> fp32 pool
// ---------------------------------------------------------------------------
__global__ void prep_bias(P20 a, const int* __restrict__ flags, float* __restrict__ bp){
    int t = threadIdx.x;
    const int src[9] = {3,5,11,13,15,7,17,9,19};
    const int off[9] = {B_OC1,B_OC2,B_FC,B_CAS1,B_CAS2,B_D1O,B_CDO,B_D1P,B_CDP};
    const int sz[9]  = {64,64,64,64,64,216,216,64,64};
    for (int s = 0; s < 9; ++s)
        if (t < sz[s]) bp[off[s] + t] = ld(a.p[src[s]], t, flags[src[s]]);
}

// ---------------------------------------------------------------------------
// MFMA implicit-GEMM 3x3 conv (pad=1). Block: 256 thr = 4 waves, tile 64oc x 64px.
// ACT: 0=none, 1=lrelu, 2=dcn-offset epilogue (sigmoid for oc>=144).
// ---------------------------------------------------------------------------
__global__ __launch_bounds__(256)
void conv_mfma(const void* __restrict__ inA, const void* __restrict__ inB,
               const bf16* __restrict__ wA, const float* __restrict__ bias,
               bf16* __restrict__ out,
               int CinA, int CinB, int CoutReal, int OutChStore, int ACT,
               const int* __restrict__ flags, int fiA, int fiB)
{
    extern __shared__ __align__(16) char smem_raw[];
    bf16* s_in = (bf16*)smem_raw;

    const int CinT  = CinA + CinB;
    const int ciPad = CinT + 4;                 // 68 or 132
    const int b     = blockIdx.z;
    const int pix0  = blockIdx.x * 64;          // 64 px, same row (192%64==0)
    const int h     = pix0 / Wn;
    const int x0    = pix0 - h*Wn;
    const int ocBase= blockIdx.y * 64;
    const int tid   = threadIdx.x;
    const int fA = (fiA>=0)?flags[fiA]:0;
    const int fB = (fiB>=0)?flags[fiB]:0;

    const int total = 3*66*CinT;
    for (int idx = tid; idx < total; idx += 256){
        int c  = idx % 66;
        int r  = idx / 66;
        int ky = r % 3;
        int ci = r / 3;
        int y  = h - 1 + ky;
        int xx = x0 - 1 + c;
        float v = 0.f;
        if ((unsigned)y < (unsigned)Hn && (unsigned)xx < (unsigned)Wn){
            if (ci < CinA) v = ld(inA, ((size_t)b*CinA + ci)*HWn + y*Wn + xx, fA);
            else           v = ld(inB, ((size_t)b*CinB + (ci-CinA))*HWn + y*Wn + xx, fB);
        }
        s_in[(ky*66 + c)*ciPad + ci] = f2b(v);
    }
    __syncthreads();

    const int w    = tid >> 6;
    const int lane = tid & 63;
    const int m    = lane & 31;
    const int half = lane >> 5;
    const int och  = (w >> 1) * 32;
    const int pxh  = (w & 1) * 32;
    const int KK   = CinT >> 4;
    const int ocb  = blockIdx.y*2 + (w >> 1);

    floatx16 acc;
#pragma unroll
    for (int r = 0; r < 16; ++r) acc[r] = 0.f;

    const bf16* wAb = wA + ((size_t)ocb*9*KK)*512 + m*16 + half*8;
    const int col0 = pxh + m;

#pragma unroll
    for (int tap = 0; tap < 9; ++tap){
        const int ky = tap/3, kx = tap - (tap/3)*3;
        const bf16* srow = s_in + (ky*66 + col0 + kx)*ciPad + half*8;
        for (int kk = 0; kk < KK; ++kk){
            B8 ba; ba.u4 = *(const uint4*)(wAb + (size_t)(tap*KK + kk)*512);
            B8 bb;
            const bf16* sp = srow + kk*16;
            bb.u2[0] = *(const uint2*)(sp);
            bb.u2[1] = *(const uint2*)(sp + 4);
            acc = __builtin_amdgcn_mfma_f32_32x32x16_bf16(ba.s8, bb.s8, acc, 0, 0, 0);
        }
    }

    const int pxo = pix0 + pxh + m;
#pragma unroll
    for (int r = 0; r < 16; ++r){
        int row = (r & 3) + 8*(r >> 2) + 4*half;
        int oc  = ocBase + och + row;
        if (oc < CoutReal){
            float v = acc[r] + bias[oc];
            if (ACT == 1) v = (v >= 0.f) ? v : 0.1f*v;
            else if (ACT == 2 && oc >= 144) v = 1.f/(1.f + expf(-v));
            out[((size_t)b*OutChStore + oc)*HWn + pxo] = f2b(v);
        }
    }
}

// ---------------------------------------------------------------------------
// DCN sample + MFMA projection. Block: 256 thr, 64 px (one row segment).
// Phase B: stage x-patch (64ch x 8rows x 72cols) into LDS (coalesced).
// Phase C: bilinear gathers from LDS (global fallback for out-of-window
//          offsets — statistically negligible); masks pre-sigmoided.
// Phase D: out[64oc][64px] = W(64x576) x samples via 32x32x16 MFMA.
// LDS: patch 73728 B + samples 74240 B = 147968 B -> 1 block/CU.
// ---------------------------------------------------------------------------
#define PROWS 8
#define PCOLS 72
__global__ __launch_bounds__(256)
void dcn_mfma(const void* __restrict__ x,      // sampled input [B][64][HW]
              const bf16* __restrict__ offs,   // [B][216][HW] bf16 (masks sigmoided)
              const bf16* __restrict__ wP,     // A-frag layout, K natural
              const float* __restrict__ pbias, // [64]
              void* __restrict__ out, int outF32, int ACT,
              const int* __restrict__ flags, int fiX)
{
    extern __shared__ __align__(16) char smem_raw[];
    bf16* s_patch = (bf16*)smem_raw;                 // [64][8][72]
    bf16* s_samp  = (bf16*)(smem_raw + 64*PROWS*PCOLS*2);  // [64][580]

    const int fX   = (fiX>=0)?flags[fiX]:0;
    const int b    = blockIdx.y;
    const int pix0 = blockIdx.x * 64;
    const int h    = pix0 / Wn;
    const int x0   = pix0 - h*Wn;
    const int tid  = threadIdx.x;
    const int ylo  = h - 3;
    const int xlo  = x0 - 3;

    // ---- Phase B: stage patch ----
    {
        const size_t xb = (size_t)b*NF*HWn;
        for (int idx = tid; idx < 64*PROWS*PCOLS; idx += 256){
            int c  = idx % PCOLS;
            int t  = idx / PCOLS;
            int r  = t & (PROWS-1);
            int ci = t >> 3;
            int y  = ylo + r;
            int xx = xlo + c;
            float v = 0.f;
            if ((unsigned)y < (unsigned)Hn && (unsigned)xx < (unsigned)Wn)
                v = ld(x, xb + (size_t)ci*HWn + y*Wn + xx, fX);
            s_patch[idx] = f2b(v);
        }
    }
    __syncthreads();

    // ---- Phase C: sampling ----
    {
        const int px = tid & 63;
        const int wq = tid >> 6;
        const size_t obase = (size_t)b*216*HWn + pix0 + px;
        const float fx = (float)(x0 + px - 1);
        for (int dt = wq*18; dt < wq*18 + 18; ++dt){
            int dg  = dt / 9;
            int tap = dt - dg*9;
            int ky  = tap / 3;
            int kx  = tap - ky*3;
            float dy = b2f(offs[obase + (size_t)(dg*18 + tap*2    )*HWn]);
            float dx = b2f(offs[obase + (size_t)(dg*18 + tap*2 + 1)*HWn]);
            float mk = b2f(offs[obase + (size_t)(144 + dg*9 + tap )*HWn]);
            float py  = dy + (float)(h - 1 + ky);
            float pxx = dx + fx + (float)kx;
            float y0f = floorf(py), x0f = floorf(pxx);
            int   y0  = (int)y0f,   xi0 = (int)x0f;
            float wy  = py - y0f,   wx  = pxx - x0f;
            float w00 = (1.f-wy)*(1.f-wx)*mk, w01 = (1.f-wy)*wx*mk;
            float w10 = wy*(1.f-wx)*mk,       w11 = wy*wx*mk;
            bf16* sout = s_samp + px*580 + dg*72 + tap;   // (dg*8+cg)*9+tap
            bool inw = (y0 >= ylo) && (y0 <= ylo + PROWS - 2) &&
                       (xi0 >= xlo) && (xi0 <= xlo + PCOLS - 2);
            if (inw){
                int p0 = (y0 - ylo)*PCOLS + (xi0 - xlo) + (dg*8)*(PROWS*PCOLS);
#pragma unroll
                for (int cg = 0; cg < 8; ++cg){
                    float v00 = b2f(s_patch[p0]);
                    float v01 = b2f(s_patch[p0 + 1]);
                    float v10 = b2f(s_patch[p0 + PCOLS]);
                    float v11 = b2f(s_patch[p0 + PCOLS + 1]);
                    sout[cg*9] = f2b(w00*v00 + w01*v01 + w10*v10 + w11*v11);
                    p0 += PROWS*PCOLS;
                }
            } else {
                bool y0v = (unsigned)y0     < (unsigned)Hn;
                bool y1v = (unsigned)(y0+1) < (unsigned)Hn;
                bool x0v = (unsigned)xi0     < (unsigned)Wn;
                bool x1v = (unsigned)(xi0+1) < (unsigned)Wn;
                int r0 = y0*Wn + xi0, r1 = r0 + Wn;
                size_t cb = ((size_t)b*NF + dg*8)*HWn;
#pragma unroll
                for (int cg = 0; cg < 8; ++cg){
                    float v00 = (y0v&&x0v) ? ld(x, cb + r0,     fX) : 0.f;
                    float v01 = (y0v&&x1v) ? ld(x, cb + r0 + 1, fX) : 0.f;
                    float v10 = (y1v&&x0v) ? ld(x, cb + r1,     fX) : 0.f;
                    float v11 = (y1v&&x1v) ? ld(x, cb + r1 + 1, fX) : 0.f;
                    sout[cg*9] = f2b(w00*v00 + w01*v01 + w10*v10 + w11*v11);
                    cb += HWn;
                }
            }
        }
    }
    __syncthreads();

    // ---- Phase D: projection GEMM ----
    const int w    = tid >> 6;
    const int lane = tid & 63;
    const int m    = lane & 31;
    const int half = lane >> 5;
    const int och  = (w >> 1) * 32;
    const int pxh  = (w & 1) * 32;

    floatx16 acc;
#pragma unroll
    for (int r = 0; r < 16; ++r) acc[r] = 0.f;

    const bf16* wPb = wP + ((size_t)(w>>1)*36)*512 + m*16 + half*8;
    const bf16* srow = s_samp + (pxh + m)*580 + half*8;
#pragma unroll 4
    for (int kk = 0; kk < 36; ++kk){
        B8 ba; ba.u4 = *(const uint4*)(wPb + (size_t)kk*512);
        B8 bb;
        const bf16* sp = srow + kk*16;
        bb.u2[0] = *(const uint2*)(sp);
        bb.u2[1] = *(const uint2*)(sp + 4);
        acc = __builtin_amdgcn_mfma_f32_32x32x16_bf16(ba.s8, bb.s8, acc, 0, 0, 0);
    }

    const int pxo = pix0 + pxh + m;
#pragma unroll
    for (int r = 0; r < 16; ++r){
        int row = (r & 3) + 8*(r >> 2) + 4*half;
        int oc  = och + row;
        float v = acc[r] + pbias[oc];
        if (ACT) v = (v >= 0.f) ? v : 0.1f*v;
        size_t oi = ((size_t)b*NF + oc)*HWn + pxo;
        if (outF32) ((float*)out)[oi] = v;
        else        ((bf16*) out)[oi] = f2b(v);
    }
}

// ---------------------------------------------------------------------------
extern "C" void kernel_launch(void* const* d_in, const int* in_sizes, int n_in,
                              void* d_out, int out_size, void* d_ws, size_t ws_size,
                              hipStream_t stream)
{
    enum { I_NBR=0, I_REF=1, I_OC1W=2, I_OC2W=4, I_D1OW=6, I_D1W=8, I_FCW=10,
           I_C1W=12, I_C2W=14, I_CDOW=16, I_CDW=18 };

    int*   flags = (int*)d_ws;
    float* bp    = (float*)((char*)d_ws + BIAS_OFF);
    bf16*  wp    = (bf16*) ((char*)d_ws + WPOOL_OFF);
    bf16*  t1    = (bf16*) ((char*)d_ws + BUF_OFF);
    bf16*  f1    = (bf16*) ((char*)d_ws + BUF_OFF + FEAT_BYTES);
    bf16*  offs  = (bf16*) ((char*)d_ws + BUF_OFF + 2*(size_t)FEAT_BYTES);
    bf16*  t0    = (bf16*) d_out;   // fp32-sized out doubles as bf16 scratch

    P20 a;
    for (int i = 0; i < 20; ++i){ a.p[i] = d_in[i]; a.n[i] = in_sizes[i]; }

    detect_kernel<<<1, 64, 0, stream>>>(a, flags);
    prep_bias<<<1, 256, 0, stream>>>(a, flags, bp);
    prep_convA<<<288, 256, 0, stream>>>(d_in[I_OC1W], flags, I_OC1W, wp+WA_OC1, 128, 64, 2);
    prep_convA<<<144, 256, 0, stream>>>(d_in[I_OC2W], flags, I_OC2W, wp+WA_OC2,  64, 64, 2);
    prep_convA<<<144, 256, 0, stream>>>(d_in[I_FCW],  flags, I_FCW,  wp+WA_FC,   64, 64, 2);
    prep_convA<<<288, 256, 0, stream>>>(d_in[I_C1W],  flags, I_C1W,  wp+WA_CAS1,128, 64, 2);
    prep_convA<<<144, 256, 0, stream>>>(d_in[I_C2W],  flags, I_C2W,  wp+WA_CAS2, 64, 64, 2);
    prep_convA<<<576, 256, 0, stream>>>(d_in[I_D1OW], flags, I_D1OW, wp+WA_D1O,  64, 216, 8);
    prep_convA<<<576, 256, 0, stream>>>(d_in[I_CDOW], flags, I_CDOW, wp+WA_CDO,  64, 216, 8);
    prep_projA<<<144, 256, 0, stream>>>(d_in[I_D1W],  flags, I_D1W,  wp+WP_D1);
    prep_projA<<<144, 256, 0, stream>>>(d_in[I_CDW],  flags, I_CDW,  wp+WP_CD);

    dim3 blk(256,1,1);
    const int smem64  = 3*66*68*2;        // 26928 B
    const int smem128 = 3*66*132*2;       // 52272 B
    const int smemD   = 64*PROWS*PCOLS*2 + 64*580*2;   // 147968 B
    dim3 g64 (576, 1, Bn);
    dim3 g216(576, 4, Bn);
    dim3 gD  (576, Bn, 1);

    // 1. t0 = lrelu(conv(cat(nbr,ref), oc1))
    conv_mfma<<<g64, blk, smem128, stream>>>(d_in[I_NBR], d_in[I_REF], wp+WA_OC1, bp+B_OC1,
        t0, 64, 64, 64, 64, 1, flags, I_NBR, I_REF);
    // 2. t1 = lrelu(conv(t0, oc2))
    conv_mfma<<<g64, blk, smem64, stream>>>(t0, nullptr, wp+WA_OC2, bp+B_OC2,
        t1, 64, 0, 64, 64, 1, flags, -1, -1);
    // 3. offs = conv(t1, d1o)  [offsets raw, masks sigmoided via ACT=2]
    conv_mfma<<<g216, blk, smem64, stream>>>(t1, nullptr, wp+WA_D1O, bp+B_D1O,
        offs, 64, 0, 216, 216, 2, flags, -1, -1);
    // 4. t1 = dcn(x=nbr, offs; proj d1)
    dcn_mfma<<<gD, blk, smemD, stream>>>(d_in[I_NBR], offs, wp+WP_D1, bp+B_D1P,
        t1, 0, 0, flags, I_NBR);
    // 5. f1 = conv(t1, fc)  (no act)
    conv_mfma<<<g64, blk, smem64, stream>>>(t1, nullptr, wp+WA_FC, bp+B_FC,
        f1, 64, 0, 64, 64, 0, flags, -1, -1);
    // 6. t0 = lrelu(conv(cat(f1, ref), cas1))
    conv_mfma<<<g64, blk, smem128, stream>>>(f1, d_in[I_REF], wp+WA_CAS1, bp+B_CAS1,
        t0, 64, 64, 64, 64, 1, flags, -1, I_REF);
    // 7. t1 = lrelu(conv(t0, cas2))
    conv_mfma<<<g64, blk, smem64, stream>>>(t0, nullptr, wp+WA_CAS2, bp+B_CAS2,
        t1, 64, 0, 64, 64, 1, flags, -1, -1);
    // 8. offs = conv(t1, cdo)  [ACT=2]
    conv_mfma<<<g216, blk, smem64, stream>>>(t1, nullptr, wp+WA_CDO, bp+B_CDO,
        offs, 64, 0, 216, 216, 2, flags, -1, -1);
    // 9. d_out = lrelu(dcn(x=f1, offs; proj cd))  fp32
    dcn_mfma<<<gD, blk, smemD, stream>>>(f1, offs, wp+WP_CD, bp+B_CDP,
        d_out, 1, 1, flags, -1);
}